// Round 10
// baseline (177.890 us; speedup 1.0000x reference)
//
#include <hip/hip_runtime.h>
#include <math.h>

// Problem constants (match reference)
#define BB 8
#define AA 512
#define NBH 64
#define FF 128
#define GG 50
#define CUTOFF 5.0f

typedef __attribute__((ext_vector_type(8)))  short bf16x8;   // 8 bf16 = 4 VGPRs
typedef __attribute__((ext_vector_type(4)))  float f32x4;    // 16x16 MFMA C/D
typedef __attribute__((ext_vector_type(16))) float f32x16;   // 32x32 MFMA C/D

#define MST 136   // M_s row stride (shorts); with XOR swizzle reads/writes are conflict-light

// Packed weight sizes (bf16 elems)
#define WV_ELEMS  (4*8*64*8)   // 16384 : Wv, 32-col B-frag layout, K=128 (8 steps of 16)
#define WQO_ELEMS (8*4*64*8)   // 16384 : Wq/Wo, 16-col B-frag layout, K=128 (4 steps of 32)
#define WF_ELEMS  (4*4*64*8)   // 8192  : W_filt, 32-col layout, K=64 pad; row 50 = b_filt

// RNE (prep only — off critical path)
__device__ __forceinline__ short f2bf(float f) {
    union { float f; unsigned u; } v; v.f = f;
    unsigned r = v.u + 0x7fffu + ((v.u >> 16) & 1u);
    return (short)(r >> 16);
}
// fast round-half-up (2 VALU)
__device__ __forceinline__ short f2bf_fast(float f) {
    return (short)((__float_as_uint(f) + 0x8000u) >> 16);
}
// pack 2 floats -> 2 bf16 in one dword: 2 adds + 1 v_perm (low short = a, high = b)
__device__ __forceinline__ unsigned int pk2bf(float a, float b) {
    unsigned int ua = __float_as_uint(a) + 0x8000u;
    unsigned int ub = __float_as_uint(b) + 0x8000u;
    return __builtin_amdgcn_perm(ub, ua, 0x07060302u);
}
// Load 8 consecutive floats (8B-aligned) from global -> bf16x8 A-fragment (packed cvt)
__device__ __forceinline__ bf16x8 ld_f8_bfpk(const float* p) {
    const float2* p2 = (const float2*)p;
    float2 a = p2[0], b = p2[1], c = p2[2], d = p2[3];
    union { unsigned int u[4]; bf16x8 v; } r;
    r.u[0] = pk2bf(a.x, a.y);
    r.u[1] = pk2bf(b.x, b.y);
    r.u[2] = pk2bf(c.x, c.y);
    r.u[3] = pk2bf(d.x, d.y);
    return r.v;
}
__device__ __forceinline__ int swz(int n) { return ((n >> 3) & 3) << 3; }  // LDS k-index XOR swizzle
__device__ __forceinline__ float dot4(float4 a, float4 b, float acc) {
    acc = fmaf(a.x, b.x, acc); acc = fmaf(a.y, b.y, acc);
    acc = fmaf(a.z, b.z, acc); acc = fmaf(a.w, b.w, acc);
    return acc;
}

// ---------------- prep: pack Wv (32-col), Wq/Wo (16-col), W_filt (32-col, K-pad) ----
// 32-col layout (Wv/Wf): dst[((w*S+s)*64+l)*8+j] = W[16s + (l>>5)*8 + j][32w + (l&31)]
// 16-col layout (Wq/Wo): dst[((c*4+s)*64+l)*8+j] = W[32s + (l>>4)*8 + j][16c + (l&15)]
// Wf K-pad rows 50..63: row 50 carries b_filt (A supplies 1.0 there), 51..63 zero.
__global__ void prep_kernel(const float* __restrict__ Wv,
                            const float* __restrict__ Wq,
                            const float* __restrict__ Wo,
                            const float* __restrict__ Wf,
                            const float* __restrict__ b_filt,
                            short* __restrict__ ws)
{
    int gid = blockIdx.x * blockDim.x + threadIdx.x;
    if (gid < WV_ELEMS) {
        int idx = gid;
        int j = idx & 7, l = (idx >> 3) & 63, rest = idx >> 9;
        int s = rest & 7, w = rest >> 3;
        int k = 16 * s + ((l >> 5) << 3) + j;
        int n = 32 * w + (l & 31);
        ws[gid] = f2bf(Wv[k * FF + n]);
    } else if (gid < WV_ELEMS + 2 * WQO_ELEMS) {
        int idx2 = gid - WV_ELEMS;
        const float* src = (idx2 < WQO_ELEMS) ? Wq : Wo;
        int idx = idx2 & (WQO_ELEMS - 1);
        int j = idx & 7, l = (idx >> 3) & 63, rest = idx >> 9;
        int s = rest & 3, c = rest >> 2;
        int k = 32 * s + (l >> 4) * 8 + j;
        int n = 16 * c + (l & 15);
        ws[gid] = f2bf(src[k * FF + n]);
    } else {
        int idx = gid - WV_ELEMS - 2 * WQO_ELEMS;
        int j = idx & 7, l = (idx >> 3) & 63, rest = idx >> 9;
        int s = rest & 3, w = rest >> 2;
        int k = 16 * s + ((l >> 5) << 3) + j;
        int n = 32 * w + (l & 31);
        float v = (k < GG) ? Wf[k * FF + n] : (k == GG ? b_filt[n] : 0.0f);
        ws[gid] = f2bf(v);
    }
}

// ---------------- main: one block per atom, 4 waves, 2 barriers ----------------
// Wave w owns cols [32w, 32w+32) == heads {2w, 2w+1}, all 64 neighbors.
// 32x32x16 layouts: A[m=lane&31][k=(lane>>5)*8+j]  B[k][n=lane&31]
//                   D: col=lane&31, row=(reg&3)+8*(reg>>2)+4*(lane>>5)
// Scores: score_n(h) = sum_i M[n,i]*kq_h[i] with kq_h = 0.25*Wk_h^T q_h.
// kq is computed PRE-barrier (waves staggered; Wk-load latency hidden by the
// filter phase) -- R8 placed it post-barrier and all waves stalled together.
// launch_bounds min-waves=4 (128-reg cap): 6 forced catastrophic spill (R6:
// WRITE_SIZE 405 MB). wacc/vacc mt-split (16 AGPR live) + kacc merged into sc
// to pull unified VGPR+AGPR under 128 for 4 waves/SIMD.
__global__ __launch_bounds__(256, 4)
void tdt_main(const float* __restrict__ x,
              const float* __restrict__ r_ij,
              const float* __restrict__ f_ij,
              const float* __restrict__ bo,
              const int*   __restrict__ neighbors,
              const int*   __restrict__ nmask,
              const float* __restrict__ Wk,
              const short* __restrict__ WvB,
              const short* __restrict__ WqB,
              const short* __restrict__ WoB,
              const short* __restrict__ WfB,
              float* __restrict__ out)
{
    const int ba   = blockIdx.x;          // 0..4095
    const int b    = ba >> 9;
    const int tid  = threadIdx.x;
    const int lane = tid & 63;
    const int w    = tid >> 6;            // wave 0..3
    const int l15  = lane & 15;
    const int quad = lane >> 4;
    const int l31  = lane & 31;
    const int khalf = (lane >> 5) << 3;   // 0 or 8
    const int w5_4  = (lane >> 5) * 4;

    __shared__ short M_s[NBH * MST];      // modulated messages, swizzled (17.4 KB)
    __shared__ float q_s[FF];             // fp32 q, written by quad==0 lanes of owner wave
    __shared__ short kq_s[4 * 256];       // per-wave [hloc][128] bf16, 0.25-scaled
    __shared__ short msg_bf[FF];

    const float* xrow = x + (size_t)ba * FF;   // this atom's features
    const float* xb   = x + (size_t)b * AA * FF;
    const size_t bao  = (size_t)ba;

    // per-lane neighbor metadata in REGISTERS (no LDS, no barrier):
    int   nbr_reg = neighbors[bao * NBH + lane];
    float C_reg;
    {
        float r = r_ij[bao * NBH + lane];
        float c = 0.5f * (__cosf((float)M_PI * r * (1.0f / CUTOFF)) + 1.0f);
        C_reg = (r < CUTOFF) ? c : 0.0f;
    }
    unsigned long long mask64 = __ballot(nmask[bao * NBH + lane] != 0);

    // ---------------- phase 1a: q via 16x16x32 MFMA (broadcast-A from global x) -----
    {
        bf16x8 xa[4];
#pragma unroll
        for (int s = 0; s < 4; ++s)
            xa[s] = ld_f8_bfpk(xrow + 32 * s + quad * 8);
#pragma unroll
        for (int ct = 0; ct < 2; ++ct) {
            int cg = 2 * w + ct;
            f32x4 z = {0.f, 0.f, 0.f, 0.f};
#pragma unroll
            for (int s = 0; s < 4; ++s) {
                bf16x8 bq = *(const bf16x8*)&WqB[((cg * 4 + s) * 64 + lane) * 8];
                z = __builtin_amdgcn_mfma_f32_16x16x32_bf16(xa[s], bq, z, 0, 0, 0);
            }
            if (quad == 0) q_s[cg * 16 + l15] = z[0];   // own wave's cols only
        }
    }

    // ---------------- phase 1k: kq = 0.25 * Wk_h^T q_h (VALU, own-wave LDS only) ----
    // Issued here so the Wk loads + LDS round-trip overlap with phase 1b below;
    // waves are staggered (no barrier between 1a and 2a).
    {
        const int hloc = lane >> 5;            // 0/1
        const int head = 2 * w + hloc;
        const int i0   = (lane & 31) * 4;
        const float4* qv4 = (const float4*)&q_s[head * 16];
        float4 qA = qv4[0], qB = qv4[1], qC = qv4[2], qD = qv4[3];
        float kqv[4];
#pragma unroll
        for (int p = 0; p < 4; ++p) {
            const float4* wr = (const float4*)&Wk[(size_t)(i0 + p) * FF + head * 16];
            float acc = dot4(wr[0], qA, 0.0f);
            acc = dot4(wr[1], qB, acc);
            acc = dot4(wr[2], qC, acc);
            acc = dot4(wr[3], qD, acc);
            kqv[p] = acc * 0.25f;              // fold 1/sqrt(DH)
        }
        uint2 pk;
        pk.x = pk2bf(kqv[0], kqv[1]);
        pk.y = pk2bf(kqv[2], kqv[3]);
        *(uint2*)&kq_s[w * 256 + hloc * 128 + i0] = pk;   // same-wave consumption only
    }

    // ---------------- phase 1b: filter 32x32x16 MFMA (A from global f_ij), mt-split -
    {
        const float* fm0 = f_ij + bao * (size_t)(NBH * GG) + (size_t)l31 * GG;
        int c = 32 * w + l31;
#pragma unroll
        for (int mt = 0; mt < 2; ++mt) {
            f32x16 wacc;
#pragma unroll
            for (int r = 0; r < 16; ++r) wacc[r] = 0.0f;
            const float* fm = fm0 + mt * 32 * GG;
#pragma unroll
            for (int s = 0; s < 4; ++s) {
                bf16x8 bfw = *(const bf16x8*)&WfB[((w * 4 + s) * 64 + lane) * 8];
                bf16x8 fa;
                if (s < 3) {
                    fa = ld_f8_bfpk(fm + 16 * s + khalf);
                } else {
                    // k = 48 + khalf + j; k<50 real data, k==50 bias row (A=1.0)
#pragma unroll
                    for (int jj = 0; jj < 8; ++jj) fa[jj] = 0;
                    if (lane < 32) {
                        fa[0] = f2bf_fast(fm[48]);
                        fa[1] = f2bf_fast(fm[49]);
                        fa[2] = (short)0x3F80;   // 1.0bf16 -> adds b_filt row
                    }
                }
                wacc = __builtin_amdgcn_mfma_f32_32x32x16_bf16(fa, bfw, wacc, 0, 0, 0);
            }
            // modulate + gather + write M_s (neighbor meta via register shuffles)
#pragma unroll
            for (int r = 0; r < 16; ++r) {
                int   n   = 32 * mt + (r & 3) + 8 * (r >> 2) + w5_4;
                int   nbn = __shfl(nbr_reg, n, 64);
                float cn  = __shfl(C_reg, n, 64);
                float xv  = xb[(size_t)nbn * FF + c];   // 128B segments, coalesced
                M_s[n * MST + (c ^ swz(n))] = f2bf_fast(wacc[r] * cn * xv);
            }
        }
    }
    __syncthreads();   // M_s ready

    // ---------------- phase 2a: scores = M_s x kq via 32x32x16 MFMA -> softmax ------
    // B cols carry kq[head(col)] -> D lands the score for the lane's own head.
    f32x16 sc[2];
#pragma unroll
    for (int mt = 0; mt < 2; ++mt)
#pragma unroll
        for (int r = 0; r < 16; ++r) sc[mt][r] = 0.0f;
    {
        const short* kqb = &kq_s[w * 256 + (l31 >> 4) * 128];
#pragma unroll
        for (int s = 0; s < 8; ++s) {
            bf16x8 bkq = *(const bf16x8*)&kqb[16 * s + khalf];   // broadcast, conflict-free
            int kb = 16 * s + khalf;
#pragma unroll
            for (int mt = 0; mt < 2; ++mt) {
                int m = 32 * mt + l31;
                bf16x8 ma = *(const bf16x8*)&M_s[m * MST + (kb ^ swz(m))];
                sc[mt] = __builtin_amdgcn_mfma_f32_32x32x16_bf16(ma, bkq, sc[mt], 0, 0, 0);
            }
        }
    }
    float inv;
    {
#pragma unroll
        for (int mt = 0; mt < 2; ++mt)
#pragma unroll
            for (int r = 0; r < 16; ++r) {
                int n = 32 * mt + (r & 3) + 8 * (r >> 2) + w5_4;
                if (!((mask64 >> n) & 1ull)) sc[mt][r] = -1e9f;
            }
        float mx = -1e30f;
#pragma unroll
        for (int mt = 0; mt < 2; ++mt)
#pragma unroll
            for (int r = 0; r < 16; ++r) mx = fmaxf(mx, sc[mt][r]);
        mx = fmaxf(mx, __shfl_xor(mx, 32, 64));
        float sum = 0.0f;
#pragma unroll
        for (int mt = 0; mt < 2; ++mt)
#pragma unroll
            for (int r = 0; r < 16; ++r) {
                float e = __expf(sc[mt][r] - mx);
                sc[mt][r] = e;
                sum += e;
            }
        sum += __shfl_xor(sum, 32, 64);
        inv = 1.0f / sum;
    }

    // ---------------- phase 2b: v MFMA fused into msg (one mt tile live at a time) --
    {
        float acc = 0.0f;
#pragma unroll
        for (int mt = 0; mt < 2; ++mt) {
            f32x16 vacc;
#pragma unroll
            for (int r = 0; r < 16; ++r) vacc[r] = 0.0f;
            int m = 32 * mt + l31;
#pragma unroll
            for (int s = 0; s < 8; ++s) {
                bf16x8 bv = *(const bf16x8*)&WvB[((w * 8 + s) * 64 + lane) * 8];
                int kb = 16 * s + khalf;
                bf16x8 ma = *(const bf16x8*)&M_s[m * MST + (kb ^ swz(m))];
                vacc = __builtin_amdgcn_mfma_f32_32x32x16_bf16(ma, bv, vacc, 0, 0, 0);
            }
#pragma unroll
            for (int r = 0; r < 16; ++r)
                acc = fmaf(sc[mt][r], vacc[r], acc);
        }
        acc += __shfl_xor(acc, 32, 64);
        if (lane < 32) msg_bf[32 * w + l31] = f2bf_fast(acc * inv);
    }
    __syncthreads();   // msg_bf ready

    // ---------------- phase 3: out = msg.Wo + x + bo (16x16x32, broadcast-A) --------
    {
        bf16x8 mga[4];
#pragma unroll
        for (int s = 0; s < 4; ++s)
            mga[s] = *(const bf16x8*)&msg_bf[s * 32 + quad * 8];
#pragma unroll
        for (int ct = 0; ct < 2; ++ct) {
            int cg = 2 * w + ct;
            f32x4 z = {0.f, 0.f, 0.f, 0.f};
#pragma unroll
            for (int s = 0; s < 4; ++s) {
                bf16x8 bw = *(const bf16x8*)&WoB[((cg * 4 + s) * 64 + lane) * 8];
                z = __builtin_amdgcn_mfma_f32_16x16x32_bf16(mga[s], bw, z, 0, 0, 0);
            }
            if (quad == 0) {
                int col = cg * 16 + l15;
                out[bao * FF + col] = z[0] + xrow[col] + bo[col];
            }
        }
    }
}

extern "C" void kernel_launch(void* const* d_in, const int* in_sizes, int n_in,
                              void* d_out, int out_size, void* d_ws, size_t ws_size,
                              hipStream_t stream) {
    // 0:e 1:x 2:t 3:r_ij 4:f_ij 5:W_filt 6:b_filt 7:Wq 8:Wk 9:Wv 10:Wo 11:bo
    // 12:neighbors 13:neighbor_mask (bool -> int32)
    const float* x      = (const float*)d_in[1];
    const float* r_ij   = (const float*)d_in[3];
    const float* f_ij   = (const float*)d_in[4];
    const float* W_filt = (const float*)d_in[5];
    const float* b_filt = (const float*)d_in[6];
    const float* Wq     = (const float*)d_in[7];
    const float* Wk     = (const float*)d_in[8];
    const float* Wv     = (const float*)d_in[9];
    const float* Wo     = (const float*)d_in[10];
    const float* bo     = (const float*)d_in[11];
    const int*   nbr    = (const int*)d_in[12];
    const int*   msk    = (const int*)d_in[13];
    float* out = (float*)d_out;

    short* ws  = (short*)d_ws;   // 57344 bf16 = 112 KB scratch
    short* WvB = ws;
    short* WqB = ws + WV_ELEMS;
    short* WoB = ws + WV_ELEMS + WQO_ELEMS;
    short* WfB = ws + WV_ELEMS + 2 * WQO_ELEMS;

    int prep_total = WV_ELEMS + 2 * WQO_ELEMS + WF_ELEMS;   // 57344 = 224 * 256
    hipLaunchKernelGGL(prep_kernel, dim3(prep_total / 256), dim3(256), 0, stream,
                       Wv, Wq, Wo, W_filt, b_filt, ws);
    hipLaunchKernelGGL(tdt_main, dim3(BB * AA), dim3(256), 0, stream,
                       x, r_ij, f_ij, bo, nbr, msk,
                       Wk, WvB, WqB, WoB, WfB, out);
}

// Round 11
// 163.055 us; speedup vs baseline: 1.0910x; 1.0910x over previous
//
#include <hip/hip_runtime.h>
#include <math.h>

// Problem constants (match reference)
#define BB 8
#define AA 512
#define NBH 64
#define FF 128
#define GG 50
#define CUTOFF 5.0f

typedef __attribute__((ext_vector_type(8)))  short bf16x8;   // 8 bf16 = 4 VGPRs
typedef __attribute__((ext_vector_type(4)))  float f32x4;    // 16x16 MFMA C/D
typedef __attribute__((ext_vector_type(16))) float f32x16;   // 32x32 MFMA C/D

#define MST 136   // M_s row stride (shorts); with XOR swizzle reads/writes are conflict-light

// Packed weight sizes (bf16 elems)
#define WKV_ELEMS (4*8*64*8)   // 16384 : Wk/Wv, 32-col B-frag layout, K=128 (8 steps of 16)
#define WQO_ELEMS (8*4*64*8)   // 16384 : Wq/Wo, 16-col B-frag layout, K=128 (4 steps of 32)
#define WF_ELEMS  (4*4*64*8)   // 8192  : W_filt, 32-col layout, K=64 pad; row 50 = b_filt
#define XB_ELEMS  (BB*AA*FF)   // 524288: x pre-converted to bf16

// RNE (prep only — off critical path)
__device__ __forceinline__ short f2bf(float f) {
    union { float f; unsigned u; } v; v.f = f;
    unsigned r = v.u + 0x7fffu + ((v.u >> 16) & 1u);
    return (short)(r >> 16);
}
// fast round-half-up (2 VALU)
__device__ __forceinline__ short f2bf_fast(float f) {
    return (short)((__float_as_uint(f) + 0x8000u) >> 16);
}
// pack 2 floats -> 2 bf16 in one dword: 2 adds + 1 v_perm
__device__ __forceinline__ unsigned int pk2bf(float a, float b) {
    unsigned int ua = __float_as_uint(a) + 0x8000u;
    unsigned int ub = __float_as_uint(b) + 0x8000u;
    return __builtin_amdgcn_perm(ub, ua, 0x07060302u);
}
// Load 8 consecutive floats (8B-aligned) from global -> bf16x8 A-fragment (packed cvt)
__device__ __forceinline__ bf16x8 ld_f8_bfpk(const float* p) {
    const float2* p2 = (const float2*)p;
    float2 a = p2[0], b = p2[1], c = p2[2], d = p2[3];
    union { unsigned int u[4]; bf16x8 v; } r;
    r.u[0] = pk2bf(a.x, a.y);
    r.u[1] = pk2bf(b.x, b.y);
    r.u[2] = pk2bf(c.x, c.y);
    r.u[3] = pk2bf(d.x, d.y);
    return r.v;
}
__device__ __forceinline__ int swz(int n) { return ((n >> 3) & 3) << 3; }  // LDS k-index XOR swizzle

// Sum over the 16-lane DPP row (VALU pipe). All 16 lanes get the sum.
__device__ __forceinline__ float row16_sum(float x) {
    int t;
    t = __builtin_amdgcn_update_dpp(0, __float_as_int(x), 0x128, 0xf, 0xf, true); x += __int_as_float(t); // row_ror:8
    t = __builtin_amdgcn_update_dpp(0, __float_as_int(x), 0x124, 0xf, 0xf, true); x += __int_as_float(t); // row_ror:4
    t = __builtin_amdgcn_update_dpp(0, __float_as_int(x), 0x122, 0xf, 0xf, true); x += __int_as_float(t); // row_ror:2
    t = __builtin_amdgcn_update_dpp(0, __float_as_int(x), 0x121, 0xf, 0xf, true); x += __int_as_float(t); // row_ror:1
    return x;
}

// ---------------- prep: pack weights into MFMA B-fragment order + x -> bf16 ---------
// 32-col layout (Wk/Wv/Wf): dst[((w*S+s)*64+l)*8+j] = W[16s + (l>>5)*8 + j][32w + (l&31)]
// 16-col layout (Wq/Wo):    dst[((c*4+s)*64+l)*8+j] = W[32s + (l>>4)*8 + j][16c + (l&15)]
// Wf K-pad rows 50..63: row 50 carries b_filt (A supplies 1.0 there), 51..63 zero.
__global__ void prep_kernel(const float* __restrict__ Wk,
                            const float* __restrict__ Wv,
                            const float* __restrict__ Wq,
                            const float* __restrict__ Wo,
                            const float* __restrict__ Wf,
                            const float* __restrict__ b_filt,
                            const float* __restrict__ x,
                            short* __restrict__ ws)
{
    int gid = blockIdx.x * blockDim.x + threadIdx.x;
    if (gid < 2 * WKV_ELEMS) {
        const float* src = (gid < WKV_ELEMS) ? Wk : Wv;
        int idx = gid & (WKV_ELEMS - 1);
        int j = idx & 7, l = (idx >> 3) & 63, rest = idx >> 9;
        int s = rest & 7, w = rest >> 3;
        int k = 16 * s + ((l >> 5) << 3) + j;
        int n = 32 * w + (l & 31);
        ws[gid] = f2bf(src[k * FF + n]);
    } else if (gid < 2 * WKV_ELEMS + 2 * WQO_ELEMS) {
        int idx2 = gid - 2 * WKV_ELEMS;
        const float* src = (idx2 < WQO_ELEMS) ? Wq : Wo;
        int idx = idx2 & (WQO_ELEMS - 1);
        int j = idx & 7, l = (idx >> 3) & 63, rest = idx >> 9;
        int s = rest & 3, c = rest >> 2;
        int k = 32 * s + (l >> 4) * 8 + j;
        int n = 16 * c + (l & 15);
        ws[gid] = f2bf(src[k * FF + n]);
    } else if (gid < 2 * WKV_ELEMS + 2 * WQO_ELEMS + WF_ELEMS) {
        int idx = gid - 2 * WKV_ELEMS - 2 * WQO_ELEMS;
        int j = idx & 7, l = (idx >> 3) & 63, rest = idx >> 9;
        int s = rest & 3, w = rest >> 2;
        int k = 16 * s + ((l >> 5) << 3) + j;
        int n = 32 * w + (l & 31);
        float v = (k < GG) ? Wf[k * FF + n] : (k == GG ? b_filt[n] : 0.0f);
        ws[gid] = f2bf(v);
    } else {
        int idx = gid - 2 * WKV_ELEMS - 2 * WQO_ELEMS - WF_ELEMS;
        ws[gid] = f2bf(x[idx]);            // xB: straight layout, (b*AA+a)*FF + col
    }
}

// ---------------- main: one block per atom, 4 waves, 2 barriers ----------------
// Wave w owns cols [32w, 32w+32) == heads {2w, 2w+1}, all 64 neighbors.
// 32x32x16 layouts: A[m=lane&31][k=(lane>>5)*8+j]  B[k][n=lane&31]
//                   D: col=lane&31, row=(reg&3)+8*(reg>>2)+4*(lane>>5)
// Phase 2 is a single fused pass per 32-row tile: A-fragments loaded ONCE feed
// both k-MFMA and v-MFMA; softmax is max-free (|score|<~20 by construction,
// exp(s) safely inside fp32; masked lanes -1e9 -> exp 0) with one final 1/sum.
// launch_bounds min-waves=4 (128-reg cap): 6 forced catastrophic spill (R6:
// WRITE_SIZE 405 MB). kq-style score tricks regressed twice (R8/R10) — keep
// row16_sum DPP reduction.
__global__ __launch_bounds__(256, 4)
void tdt_main(const float* __restrict__ x,
              const float* __restrict__ r_ij,
              const float* __restrict__ f_ij,
              const float* __restrict__ bo,
              const int*   __restrict__ neighbors,
              const int*   __restrict__ nmask,
              const short* __restrict__ WkB,
              const short* __restrict__ WvB,
              const short* __restrict__ WqB,
              const short* __restrict__ WoB,
              const short* __restrict__ WfB,
              const short* __restrict__ xB,
              float* __restrict__ out)
{
    const int ba   = blockIdx.x;          // 0..4095
    const int b    = ba >> 9;
    const int tid  = threadIdx.x;
    const int lane = tid & 63;
    const int w    = tid >> 6;            // wave 0..3
    const int l15  = lane & 15;
    const int quad = lane >> 4;
    const int l31  = lane & 31;
    const int khalf = (lane >> 5) << 3;   // 0 or 8
    const int w5_4  = (lane >> 5) * 4;

    __shared__ short M_s[NBH * MST];      // modulated messages, swizzled (17.4 KB)
    __shared__ short msg_bf[FF];

    const float* xrow = x + (size_t)ba * FF;                       // residual (fp32)
    const unsigned short* xbu = (const unsigned short*)xB + (size_t)b * AA * FF;
    const size_t bao = (size_t)ba;

    // per-lane neighbor metadata in REGISTERS (no LDS, no barrier):
    int   nbr_reg = neighbors[bao * NBH + lane];
    float C_reg;
    {
        float r = r_ij[bao * NBH + lane];
        float c = 0.5f * (__cosf((float)M_PI * r * (1.0f / CUTOFF)) + 1.0f);
        C_reg = (r < CUTOFF) ? c : 0.0f;
    }
    unsigned long long mask64 = __ballot(nmask[bao * NBH + lane] != 0);

    // ---------------- phase 1a: q via 16x16x32 MFMA (broadcast-A from xB) -----------
    // Only qvm = 0.25 * q[32w + (lane&31)] stays live downstream.
    float qvm;
    {
        const short* xbrow = &xB[(size_t)ba * FF];
        bf16x8 xa[4];
#pragma unroll
        for (int s = 0; s < 4; ++s)
            xa[s] = *(const bf16x8*)&xbrow[32 * s + quad * 8];     // raw 16B, no cvt
        float qv0, qv1;
#pragma unroll
        for (int ct = 0; ct < 2; ++ct) {
            int cg = 2 * w + ct;
            f32x4 z = {0.f, 0.f, 0.f, 0.f};
#pragma unroll
            for (int s = 0; s < 4; ++s) {
                bf16x8 bq = *(const bf16x8*)&WqB[((cg * 4 + s) * 64 + lane) * 8];
                z = __builtin_amdgcn_mfma_f32_16x16x32_bf16(xa[s], bq, z, 0, 0, 0);
            }
            if (ct == 0) qv0 = z[0]; else qv1 = z[0];
        }
        qvm = (((lane >> 4) & 1) ? qv1 : qv0) * 0.25f;             // fold 1/sqrt(DH)
    }

    // ---------------- phase 1b: filter 32x32x16 MFMA (A from global f_ij), mt-split -
    {
        const float* fm0 = f_ij + bao * (size_t)(NBH * GG) + (size_t)l31 * GG;
        int c = 32 * w + l31;
#pragma unroll
        for (int mt = 0; mt < 2; ++mt) {
            f32x16 wacc;
#pragma unroll
            for (int r = 0; r < 16; ++r) wacc[r] = 0.0f;
            const float* fm = fm0 + mt * 32 * GG;
#pragma unroll
            for (int s = 0; s < 4; ++s) {
                bf16x8 bfw = *(const bf16x8*)&WfB[((w * 4 + s) * 64 + lane) * 8];
                bf16x8 fa;
                if (s < 3) {
                    fa = ld_f8_bfpk(fm + 16 * s + khalf);
                } else {
                    // k = 48 + khalf + j; k<50 real data, k==50 bias row (A=1.0)
#pragma unroll
                    for (int jj = 0; jj < 8; ++jj) fa[jj] = 0;
                    if (lane < 32) {
                        fa[0] = f2bf_fast(fm[48]);
                        fa[1] = f2bf_fast(fm[49]);
                        fa[2] = (short)0x3F80;   // 1.0bf16 -> adds b_filt row
                    }
                }
                wacc = __builtin_amdgcn_mfma_f32_32x32x16_bf16(fa, bfw, wacc, 0, 0, 0);
            }
            // modulate + gather (bf16 x) + write M_s
#pragma unroll
            for (int r = 0; r < 16; ++r) {
                int   n   = 32 * mt + (r & 3) + 8 * (r >> 2) + w5_4;
                int   nbn = __shfl(nbr_reg, n, 64);
                float cn  = __shfl(C_reg, n, 64);
                float xv  = __uint_as_float((unsigned)xbu[(size_t)nbn * FF + c] << 16);
                M_s[n * MST + (c ^ swz(n))] = f2bf_fast(wacc[r] * cn * xv);
            }
        }
    }
    __syncthreads();   // M_s ready

    // ---------------- phase 2: fused k/v MFMA + max-free softmax + msg, per mt ------
    float sum = 0.0f, acc = 0.0f;
#pragma unroll
    for (int mt = 0; mt < 2; ++mt) {
        int m = 32 * mt + l31;
        bf16x8 ma[8];                                  // A-fragments loaded ONCE
#pragma unroll
        for (int s = 0; s < 8; ++s)
            ma[s] = *(const bf16x8*)&M_s[m * MST + ((16 * s + khalf) ^ swz(m))];
        f32x16 kacc;
#pragma unroll
        for (int r = 0; r < 16; ++r) kacc[r] = 0.0f;
#pragma unroll
        for (int s = 0; s < 8; ++s) {
            bf16x8 bk = *(const bf16x8*)&WkB[((w * 8 + s) * 64 + lane) * 8];
            kacc = __builtin_amdgcn_mfma_f32_32x32x16_bf16(ma[s], bk, kacc, 0, 0, 0);
        }
        f32x16 vacc;
#pragma unroll
        for (int r = 0; r < 16; ++r) vacc[r] = 0.0f;
#pragma unroll
        for (int s = 0; s < 8; ++s) {
            bf16x8 bv = *(const bf16x8*)&WvB[((w * 8 + s) * 64 + lane) * 8];
            vacc = __builtin_amdgcn_mfma_f32_32x32x16_bf16(ma[s], bv, vacc, 0, 0, 0);
        }
#pragma unroll
        for (int r = 0; r < 16; ++r) {
            float sr = row16_sum(kacc[r] * qvm);       // score for (n, lane's head)
            int   n  = 32 * mt + (r & 3) + 8 * (r >> 2) + w5_4;
            float e  = ((mask64 >> n) & 1ull) ? __expf(sr) : 0.0f;
            sum += e;
            acc  = fmaf(e, vacc[r], acc);
        }
    }
    sum += __shfl_xor(sum, 32, 64);                    // other 32 neighbors
    acc += __shfl_xor(acc, 32, 64);
    if (lane < 32) msg_bf[32 * w + l31] = f2bf_fast(acc / sum);
    __syncthreads();   // msg_bf ready

    // ---------------- phase 3: out = msg.Wo + x + bo (16x16x32, broadcast-A) --------
    {
        bf16x8 mga[4];
#pragma unroll
        for (int s = 0; s < 4; ++s)
            mga[s] = *(const bf16x8*)&msg_bf[s * 32 + quad * 8];
#pragma unroll
        for (int ct = 0; ct < 2; ++ct) {
            int cg = 2 * w + ct;
            f32x4 z = {0.f, 0.f, 0.f, 0.f};
#pragma unroll
            for (int s = 0; s < 4; ++s) {
                bf16x8 bw = *(const bf16x8*)&WoB[((cg * 4 + s) * 64 + lane) * 8];
                z = __builtin_amdgcn_mfma_f32_16x16x32_bf16(mga[s], bw, z, 0, 0, 0);
            }
            if (quad == 0) {
                int col = cg * 16 + l15;
                out[bao * FF + col] = z[0] + xrow[col] + bo[col];
            }
        }
    }
}

extern "C" void kernel_launch(void* const* d_in, const int* in_sizes, int n_in,
                              void* d_out, int out_size, void* d_ws, size_t ws_size,
                              hipStream_t stream) {
    // 0:e 1:x 2:t 3:r_ij 4:f_ij 5:W_filt 6:b_filt 7:Wq 8:Wk 9:Wv 10:Wo 11:bo
    // 12:neighbors 13:neighbor_mask (bool -> int32)
    const float* x      = (const float*)d_in[1];
    const float* r_ij   = (const float*)d_in[3];
    const float* f_ij   = (const float*)d_in[4];
    const float* W_filt = (const float*)d_in[5];
    const float* b_filt = (const float*)d_in[6];
    const float* Wq     = (const float*)d_in[7];
    const float* Wk     = (const float*)d_in[8];
    const float* Wv     = (const float*)d_in[9];
    const float* Wo     = (const float*)d_in[10];
    const float* bo     = (const float*)d_in[11];
    const int*   nbr    = (const int*)d_in[12];
    const int*   msk    = (const int*)d_in[13];
    float* out = (float*)d_out;

    short* ws  = (short*)d_ws;   // 73728 + 524288 bf16 = 1.17 MB scratch
    short* WkB = ws;
    short* WvB = ws + WKV_ELEMS;
    short* WqB = ws + 2 * WKV_ELEMS;
    short* WoB = ws + 2 * WKV_ELEMS + WQO_ELEMS;
    short* WfB = ws + 2 * WKV_ELEMS + 2 * WQO_ELEMS;
    short* xB  = ws + 2 * WKV_ELEMS + 2 * WQO_ELEMS + WF_ELEMS;

    int prep_total = 2 * WKV_ELEMS + 2 * WQO_ELEMS + WF_ELEMS + XB_ELEMS; // 598016 = 2336*256
    hipLaunchKernelGGL(prep_kernel, dim3(prep_total / 256), dim3(256), 0, stream,
                       Wk, Wv, Wq, Wo, W_filt, b_filt, x, ws);
    hipLaunchKernelGGL(tdt_main, dim3(BB * AA), dim3(256), 0, stream,
                       x, r_ij, f_ij, bo, nbr, msk,
                       WkB, WvB, WqB, WoB, WfB, xB, out);
}

// Round 13
// 162.958 us; speedup vs baseline: 1.0916x; 1.0006x over previous
//
#include <hip/hip_runtime.h>
#include <math.h>

// Problem constants (match reference)
#define BB 8
#define AA 512
#define NBH 64
#define FF 128
#define GG 50
#define CUTOFF 5.0f

typedef __attribute__((ext_vector_type(8)))  short bf16x8;   // 8 bf16 = 4 VGPRs
typedef __attribute__((ext_vector_type(4)))  float f32x4;    // 16x16 MFMA C/D
typedef __attribute__((ext_vector_type(16))) float f32x16;   // 32x32 MFMA C/D

#define MST 136   // M_s row stride (shorts); with XOR swizzle reads/writes are conflict-light

// Packed weight sizes (bf16 elems)
#define WKV_ELEMS (4*8*64*8)   // 16384 : Wk/Wv, 32-col B-frag layout, K=128 (8 steps of 16)
#define WQO_ELEMS (8*4*64*8)   // 16384 : Wq/Wo, 16-col B-frag layout, K=128 (4 steps of 32)
#define WF_ELEMS  (4*4*64*8)   // 8192  : W_filt, 32-col layout, K=64 pad; row 50 = b_filt
#define XB_ELEMS  (BB*AA*FF)   // 524288: x pre-converted to bf16

// RNE (prep only — off critical path)
__device__ __forceinline__ short f2bf(float f) {
    union { float f; unsigned u; } v; v.f = f;
    unsigned r = v.u + 0x7fffu + ((v.u >> 16) & 1u);
    return (short)(r >> 16);
}
// fast round-half-up (2 VALU)
__device__ __forceinline__ short f2bf_fast(float f) {
    return (short)((__float_as_uint(f) + 0x8000u) >> 16);
}
// pack 2 floats -> 2 bf16 in one dword: 2 adds + 1 v_perm
__device__ __forceinline__ unsigned int pk2bf(float a, float b) {
    unsigned int ua = __float_as_uint(a) + 0x8000u;
    unsigned int ub = __float_as_uint(b) + 0x8000u;
    return __builtin_amdgcn_perm(ub, ua, 0x07060302u);
}
// Load 8 consecutive floats (8B-aligned) from global -> bf16x8 A-fragment (packed cvt)
__device__ __forceinline__ bf16x8 ld_f8_bfpk(const float* p) {
    const float2* p2 = (const float2*)p;
    float2 a = p2[0], b = p2[1], c = p2[2], d = p2[3];
    union { unsigned int u[4]; bf16x8 v; } r;
    r.u[0] = pk2bf(a.x, a.y);
    r.u[1] = pk2bf(b.x, b.y);
    r.u[2] = pk2bf(c.x, c.y);
    r.u[3] = pk2bf(d.x, d.y);
    return r.v;
}
__device__ __forceinline__ int swz(int n) { return ((n >> 3) & 3) << 3; }  // LDS k-index XOR swizzle

// Sum over the 16-lane DPP row (VALU pipe). All 16 lanes get the sum.
__device__ __forceinline__ float row16_sum(float x) {
    int t;
    t = __builtin_amdgcn_update_dpp(0, __float_as_int(x), 0x128, 0xf, 0xf, true); x += __int_as_float(t); // row_ror:8
    t = __builtin_amdgcn_update_dpp(0, __float_as_int(x), 0x124, 0xf, 0xf, true); x += __int_as_float(t); // row_ror:4
    t = __builtin_amdgcn_update_dpp(0, __float_as_int(x), 0x122, 0xf, 0xf, true); x += __int_as_float(t); // row_ror:2
    t = __builtin_amdgcn_update_dpp(0, __float_as_int(x), 0x121, 0xf, 0xf, true); x += __int_as_float(t); // row_ror:1
    return x;
}

// ---------------- prep: pack weights into MFMA B-fragment order + x -> bf16 ---------
// 32-col layout (Wk/Wv/Wf): dst[((w*S+s)*64+l)*8+j] = W[16s + (l>>5)*8 + j][32w + (l&31)]
// 16-col layout (Wq/Wo):    dst[((c*4+s)*64+l)*8+j] = W[32s + (l>>4)*8 + j][16c + (l&15)]
// Wf K-pad rows 50..63: row 50 carries b_filt (A supplies 1.0 there), 51..63 zero.
__global__ void prep_kernel(const float* __restrict__ Wk,
                            const float* __restrict__ Wv,
                            const float* __restrict__ Wq,
                            const float* __restrict__ Wo,
                            const float* __restrict__ Wf,
                            const float* __restrict__ b_filt,
                            const float* __restrict__ x,
                            short* __restrict__ ws)
{
    int gid = blockIdx.x * blockDim.x + threadIdx.x;
    if (gid < 2 * WKV_ELEMS) {
        const float* src = (gid < WKV_ELEMS) ? Wk : Wv;
        int idx = gid & (WKV_ELEMS - 1);
        int j = idx & 7, l = (idx >> 3) & 63, rest = idx >> 9;
        int s = rest & 7, w = rest >> 3;
        int k = 16 * s + ((l >> 5) << 3) + j;
        int n = 32 * w + (l & 31);
        ws[gid] = f2bf(src[k * FF + n]);
    } else if (gid < 2 * WKV_ELEMS + 2 * WQO_ELEMS) {
        int idx2 = gid - 2 * WKV_ELEMS;
        const float* src = (idx2 < WQO_ELEMS) ? Wq : Wo;
        int idx = idx2 & (WQO_ELEMS - 1);
        int j = idx & 7, l = (idx >> 3) & 63, rest = idx >> 9;
        int s = rest & 3, c = rest >> 2;
        int k = 32 * s + (l >> 4) * 8 + j;
        int n = 16 * c + (l & 15);
        ws[gid] = f2bf(src[k * FF + n]);
    } else if (gid < 2 * WKV_ELEMS + 2 * WQO_ELEMS + WF_ELEMS) {
        int idx = gid - 2 * WKV_ELEMS - 2 * WQO_ELEMS;
        int j = idx & 7, l = (idx >> 3) & 63, rest = idx >> 9;
        int s = rest & 3, w = rest >> 2;
        int k = 16 * s + ((l >> 5) << 3) + j;
        int n = 32 * w + (l & 31);
        float v = (k < GG) ? Wf[k * FF + n] : (k == GG ? b_filt[n] : 0.0f);
        ws[gid] = f2bf(v);
    } else {
        int idx = gid - 2 * WKV_ELEMS - 2 * WQO_ELEMS - WF_ELEMS;
        ws[gid] = f2bf(x[idx]);            // xB: straight layout, (b*AA+a)*FF + col
    }
}

// ---------------- main: one block per atom, 4 waves, 2 barriers ----------------
// Wave w owns cols [32w, 32w+32) == heads {2w, 2w+1}, all 64 neighbors.
// 32x32x16 layouts: A[m=lane&31][k=(lane>>5)*8+j]  B[k][n=lane&31]
//                   D: col=lane&31, row=(reg&3)+8*(reg>>2)+4*(lane>>5)
// Phase 2: k-MFMA and v-MFMA interleaved per s-step — each M_s fragment is
// TRANSIENT (loaded once, feeds both, dies). R11 cached all 8 fragments
// (ma[8] = 32 VGPR) and spilled (WRITE_SIZE 14.7 MB); this keeps the halved
// DS traffic without the register spike. Softmax is max-free (|score| small
// by construction; masked -> e=0) with one final 1/sum.
// launch_bounds min-waves=4 (128-reg cap): 6 forced catastrophic spill (R6:
// WRITE_SIZE 405 MB). kq-style score tricks regressed twice (R8/R10) — keep
// row16_sum DPP reduction.
__global__ __launch_bounds__(256, 4)
void tdt_main(const float* __restrict__ x,
              const float* __restrict__ r_ij,
              const float* __restrict__ f_ij,
              const float* __restrict__ bo,
              const int*   __restrict__ neighbors,
              const int*   __restrict__ nmask,
              const short* __restrict__ WkB,
              const short* __restrict__ WvB,
              const short* __restrict__ WqB,
              const short* __restrict__ WoB,
              const short* __restrict__ WfB,
              const short* __restrict__ xB,
              float* __restrict__ out)
{
    const int ba   = blockIdx.x;          // 0..4095
    const int b    = ba >> 9;
    const int tid  = threadIdx.x;
    const int lane = tid & 63;
    const int w    = tid >> 6;            // wave 0..3
    const int l15  = lane & 15;
    const int quad = lane >> 4;
    const int l31  = lane & 31;
    const int khalf = (lane >> 5) << 3;   // 0 or 8
    const int w5_4  = (lane >> 5) * 4;

    __shared__ short M_s[NBH * MST];      // modulated messages, swizzled (17.4 KB)
    __shared__ short msg_bf[FF];

    const float* xrow = x + (size_t)ba * FF;                       // residual (fp32)
    const unsigned short* xbu = (const unsigned short*)xB + (size_t)b * AA * FF;
    const size_t bao = (size_t)ba;

    // per-lane neighbor metadata in REGISTERS (no LDS, no barrier):
    int   nbr_reg = neighbors[bao * NBH + lane];
    float C_reg;
    {
        float r = r_ij[bao * NBH + lane];
        float c = 0.5f * (__cosf((float)M_PI * r * (1.0f / CUTOFF)) + 1.0f);
        C_reg = (r < CUTOFF) ? c : 0.0f;
    }
    unsigned long long mask64 = __ballot(nmask[bao * NBH + lane] != 0);

    // ---------------- phase 1a: q via 16x16x32 MFMA (broadcast-A from xB) -----------
    // Only qvm = 0.25 * q[32w + (lane&31)] stays live downstream.
    float qvm;
    {
        const short* xbrow = &xB[(size_t)ba * FF];
        bf16x8 xa[4];
#pragma unroll
        for (int s = 0; s < 4; ++s)
            xa[s] = *(const bf16x8*)&xbrow[32 * s + quad * 8];     // raw 16B, no cvt
        float qv0, qv1;
#pragma unroll
        for (int ct = 0; ct < 2; ++ct) {
            int cg = 2 * w + ct;
            f32x4 z = {0.f, 0.f, 0.f, 0.f};
#pragma unroll
            for (int s = 0; s < 4; ++s) {
                bf16x8 bq = *(const bf16x8*)&WqB[((cg * 4 + s) * 64 + lane) * 8];
                z = __builtin_amdgcn_mfma_f32_16x16x32_bf16(xa[s], bq, z, 0, 0, 0);
            }
            if (ct == 0) qv0 = z[0]; else qv1 = z[0];
        }
        qvm = (((lane >> 4) & 1) ? qv1 : qv0) * 0.25f;             // fold 1/sqrt(DH)
    }

    // ---------------- phase 1b: filter 32x32x16 MFMA (A from global f_ij), mt-split -
    {
        const float* fm0 = f_ij + bao * (size_t)(NBH * GG) + (size_t)l31 * GG;
        int c = 32 * w + l31;
#pragma unroll
        for (int mt = 0; mt < 2; ++mt) {
            f32x16 wacc;
#pragma unroll
            for (int r = 0; r < 16; ++r) wacc[r] = 0.0f;
            const float* fm = fm0 + mt * 32 * GG;
#pragma unroll
            for (int s = 0; s < 4; ++s) {
                bf16x8 bfw = *(const bf16x8*)&WfB[((w * 4 + s) * 64 + lane) * 8];
                bf16x8 fa;
                if (s < 3) {
                    fa = ld_f8_bfpk(fm + 16 * s + khalf);
                } else {
                    // k = 48 + khalf + j; k<50 real data, k==50 bias row (A=1.0)
#pragma unroll
                    for (int jj = 0; jj < 8; ++jj) fa[jj] = 0;
                    if (lane < 32) {
                        fa[0] = f2bf_fast(fm[48]);
                        fa[1] = f2bf_fast(fm[49]);
                        fa[2] = (short)0x3F80;   // 1.0bf16 -> adds b_filt row
                    }
                }
                wacc = __builtin_amdgcn_mfma_f32_32x32x16_bf16(fa, bfw, wacc, 0, 0, 0);
            }
            // modulate + gather (bf16 x) + write M_s
#pragma unroll
            for (int r = 0; r < 16; ++r) {
                int   n   = 32 * mt + (r & 3) + 8 * (r >> 2) + w5_4;
                int   nbn = __shfl(nbr_reg, n, 64);
                float cn  = __shfl(C_reg, n, 64);
                float xv  = __uint_as_float((unsigned)xbu[(size_t)nbn * FF + c] << 16);
                M_s[n * MST + (c ^ swz(n))] = f2bf_fast(wacc[r] * cn * xv);
            }
        }
    }
    __syncthreads();   // M_s ready

    // ---------------- phase 2: interleaved k/v MFMA + max-free softmax + msg --------
    float sum = 0.0f, acc = 0.0f;
#pragma unroll
    for (int mt = 0; mt < 2; ++mt) {
        int m = 32 * mt + l31;
        f32x16 kacc, vacc;
#pragma unroll
        for (int r = 0; r < 16; ++r) { kacc[r] = 0.0f; vacc[r] = 0.0f; }
#pragma unroll
        for (int s = 0; s < 8; ++s) {
            bf16x8 ma = *(const bf16x8*)&M_s[m * MST + ((16 * s + khalf) ^ swz(m))];
            bf16x8 bk = *(const bf16x8*)&WkB[((w * 8 + s) * 64 + lane) * 8];
            bf16x8 bv = *(const bf16x8*)&WvB[((w * 8 + s) * 64 + lane) * 8];
            kacc = __builtin_amdgcn_mfma_f32_32x32x16_bf16(ma, bk, kacc, 0, 0, 0);
            vacc = __builtin_amdgcn_mfma_f32_32x32x16_bf16(ma, bv, vacc, 0, 0, 0);
        }
#pragma unroll
        for (int r = 0; r < 16; ++r) {
            float sr = row16_sum(kacc[r] * qvm);       // score for (n, lane's head)
            int   n  = 32 * mt + (r & 3) + 8 * (r >> 2) + w5_4;
            float e  = ((mask64 >> n) & 1ull) ? __expf(sr) : 0.0f;
            sum += e;
            acc  = fmaf(e, vacc[r], acc);
        }
    }
    sum += __shfl_xor(sum, 32, 64);                    // other 32 neighbors
    acc += __shfl_xor(acc, 32, 64);
    if (lane < 32) msg_bf[32 * w + l31] = f2bf_fast(acc / sum);
    __syncthreads();   // msg_bf ready

    // ---------------- phase 3: out = msg.Wo + x + bo (16x16x32, broadcast-A) --------
    {
        bf16x8 mga[4];
#pragma unroll
        for (int s = 0; s < 4; ++s)
            mga[s] = *(const bf16x8*)&msg_bf[s * 32 + quad * 8];
#pragma unroll
        for (int ct = 0; ct < 2; ++ct) {
            int cg = 2 * w + ct;
            f32x4 z = {0.f, 0.f, 0.f, 0.f};
#pragma unroll
            for (int s = 0; s < 4; ++s) {
                bf16x8 bw = *(const bf16x8*)&WoB[((cg * 4 + s) * 64 + lane) * 8];
                z = __builtin_amdgcn_mfma_f32_16x16x32_bf16(mga[s], bw, z, 0, 0, 0);
            }
            if (quad == 0) {
                int col = cg * 16 + l15;
                out[bao * FF + col] = z[0] + xrow[col] + bo[col];
            }
        }
    }
}

extern "C" void kernel_launch(void* const* d_in, const int* in_sizes, int n_in,
                              void* d_out, int out_size, void* d_ws, size_t ws_size,
                              hipStream_t stream) {
    // 0:e 1:x 2:t 3:r_ij 4:f_ij 5:W_filt 6:b_filt 7:Wq 8:Wk 9:Wv 10:Wo 11:bo
    // 12:neighbors 13:neighbor_mask (bool -> int32)
    const float* x      = (const float*)d_in[1];
    const float* r_ij   = (const float*)d_in[3];
    const float* f_ij   = (const float*)d_in[4];
    const float* W_filt = (const float*)d_in[5];
    const float* b_filt = (const float*)d_in[6];
    const float* Wq     = (const float*)d_in[7];
    const float* Wk     = (const float*)d_in[8];
    const float* Wv     = (const float*)d_in[9];
    const float* Wo     = (const float*)d_in[10];
    const float* bo     = (const float*)d_in[11];
    const int*   nbr    = (const int*)d_in[12];
    const int*   msk    = (const int*)d_in[13];
    float* out = (float*)d_out;

    short* ws  = (short*)d_ws;   // 73728 + 524288 bf16 = 1.17 MB scratch
    short* WkB = ws;
    short* WvB = ws + WKV_ELEMS;
    short* WqB = ws + 2 * WKV_ELEMS;
    short* WoB = ws + 2 * WKV_ELEMS + WQO_ELEMS;
    short* WfB = ws + 2 * WKV_ELEMS + 2 * WQO_ELEMS;
    short* xB  = ws + 2 * WKV_ELEMS + 2 * WQO_ELEMS + WF_ELEMS;

    int prep_total = 2 * WKV_ELEMS + 2 * WQO_ELEMS + WF_ELEMS + XB_ELEMS; // 598016 = 2336*256
    hipLaunchKernelGGL(prep_kernel, dim3(prep_total / 256), dim3(256), 0, stream,
                       Wk, Wv, Wq, Wo, W_filt, b_filt, x, ws);
    hipLaunchKernelGGL(tdt_main, dim3(BB * AA), dim3(256), 0, stream,
                       x, r_ij, f_ij, bo, nbr, msk,
                       WkB, WvB, WqB, WoB, WfB, xB, out);
}